// Round 4
// baseline (1597.016 us; speedup 1.0000x reference)
//
#include <hip/hip_runtime.h>
#include <hip/hip_cooperative_groups.h>
#include <math.h>

namespace cg = cooperative_groups;

// ---------------------------------------------------------------------------
// RecurrentEncoder: LSTM (B=256, D=2048, H=2048, T=32) + emission head (K=64)
// Round 4: persistent cooperative LSTM kernel.
//   - 256 blocks x 512 thr, 1 block/CU; W_hh slab (128 KB) in LDS for ALL ticks
//   - c-state and xg fragments register-resident across ticks
//   - h^T ping-pongs through global slots; grid.sync() between ticks
//   - A (h^T) streams global->register, depth-8 ring, conflict-free LDS reads
// ---------------------------------------------------------------------------

typedef short  short8  __attribute__((ext_vector_type(8)));   // 8 x bf16
typedef float  floatx4 __attribute__((ext_vector_type(4)));

#define BB 256
#define HH 2048
#define G4 8192
#define KK 64
#define TT 32

__device__ __forceinline__ unsigned short f2bf(float f) {
  union { float f; unsigned int u; } v; v.f = f;
  unsigned int u = v.u;
  u += 0x7fffu + ((u >> 16) & 1u);   // round-to-nearest-even
  return (unsigned short)(u >> 16);
}
__device__ __forceinline__ float fast_sigmoid(float x) {
  return __builtin_amdgcn_rcpf(1.0f + __expf(-x));
}
__device__ __forceinline__ float fast_tanh(float x) {
  return 2.0f * __builtin_amdgcn_rcpf(1.0f + __expf(-2.0f * x)) - 1.0f;
}
__device__ __forceinline__ float softplusf_(float x) {
  return (x > 20.0f) ? x : log1pf(__expf(x));
}
__device__ __forceinline__ short8 cvt8(const float* __restrict__ s) {
  float4 a = reinterpret_cast<const float4*>(s)[0];
  float4 b = reinterpret_cast<const float4*>(s)[1];
  short8 o;
  o[0] = f2bf(a.x); o[1] = f2bf(a.y); o[2] = f2bf(a.z); o[3] = f2bf(a.w);
  o[4] = f2bf(b.x); o[5] = f2bf(b.y); o[6] = f2bf(b.z); o[7] = f2bf(b.w);
  return o;
}

// Weight transform: fp32 [gate-major or natural][K] -> bf16 chunks
// [blk][k8 128*2][col 32][8elem].  PERM=1: col q = u*4+g <- src row g*2048+u.
template <int PERM>
__global__ void cvt_w_kernel(const float* __restrict__ in,
                             unsigned short* __restrict__ out, int total) {
  int tid = blockIdx.x * 256 + threadIdx.x;
  if (tid >= total) return;
  int col = tid & 31;
  int k4  = (tid >> 5) & 63;    // pair index: k8 = 2*k4
  int ph  = (tid >> 11) & 1;
  int blk = tid >> 12;
  int q = blk * 32 + col;
  int srcrow = PERM ? ((q & 3) * HH + (q >> 2)) : q;
  const float* src = in + (size_t)srcrow * HH + (ph * 128 + k4 * 2) * 8;
  short8 o0 = cvt8(src);
  short8 o1 = cvt8(src + 8);
  size_t ch = ((size_t)(blk * 2 + ph) * 128 + k4 * 2) * 32 + col;
  reinterpret_cast<short8*>(out)[ch]      = o0;
  reinterpret_cast<short8*>(out)[ch + 32] = o1;
}

// x fp32 [256][2048] -> x^T chunks [k8 256][row 256][8]
__global__ void cvt_x_kernel(const float* __restrict__ in,
                             unsigned short* __restrict__ out) {
  int tid = blockIdx.x * 256 + threadIdx.x;   // 65536
  int row = tid & 255, k8 = tid >> 8;
  short8 o = cvt8(in + (size_t)row * HH + k8 * 8);
  reinterpret_cast<short8*>(out)[tid] = o;    // chunk = k8*256 + row
}

// ---------------------------------------------------------------------------
// Shared GEMM core for xg/fe kernels (2-phase LDS W staging, as round 3).
// ---------------------------------------------------------------------------
__device__ __forceinline__ void core_gemm(const short8* __restrict__ A8,
                                          const short8* __restrict__ Wg8,
                                          short8* L8, floatx4 acc[2][2]) {
  const int tid = threadIdx.x;
  const int lane = tid & 63, wave = tid >> 6;
  const int l15 = lane & 15, l4 = lane >> 4;
  const short8* Lr = L8 + l4 * 32 + l15;
  const int abase = l4 * 256 + wave * 32 + l15;
  for (int ph = 0; ph < 2; ++ph) {
    __syncthreads();
#pragma unroll
    for (int j = 0; j < 8; ++j)
      L8[tid + j * 512] = Wg8[ph * 4096 + tid + j * 512];
    __syncthreads();
    short8 Ar[4][2];
#pragma unroll
    for (int i = 0; i < 4; ++i) {
      Ar[i][0] = A8[abase +      (ph * 128 + i * 4) * 256];
      Ar[i][1] = A8[abase + 16 + (ph * 128 + i * 4) * 256];
    }
#pragma unroll 8
    for (int kt = 0; kt < 32; ++kt) {
      short8 a0 = Ar[kt & 3][0], a1 = Ar[kt & 3][1];
      if (kt < 28) {
        Ar[kt & 3][0] = A8[abase +      (ph * 128 + (kt + 4) * 4) * 256];
        Ar[kt & 3][1] = A8[abase + 16 + (ph * 128 + (kt + 4) * 4) * 256];
      }
      short8 b0 = Lr[kt * 128];
      short8 b1 = Lr[kt * 128 + 16];
      acc[0][0] = __builtin_amdgcn_mfma_f32_16x16x32_bf16(a0, b0, acc[0][0], 0, 0, 0);
      acc[0][1] = __builtin_amdgcn_mfma_f32_16x16x32_bf16(a0, b1, acc[0][1], 0, 0, 0);
      acc[1][0] = __builtin_amdgcn_mfma_f32_16x16x32_bf16(a1, b0, acc[1][0], 0, 0, 0);
      acc[1][1] = __builtin_amdgcn_mfma_f32_16x16x32_bf16(a1, b1, acc[1][1], 0, 0, 0);
    }
  }
}

// ---------------------------------------------------------------------------
// Persistent LSTM: all 32 ticks in one cooperative kernel.
// Block blk owns q-cols [32blk, 32blk+32) = units [8blk, 8blk+8) x 4 gates.
// ---------------------------------------------------------------------------
__global__ __launch_bounds__(512) void lstm_kernel(
    const unsigned short* __restrict__ Whh,   // [blk][k8 256][col 32] chunks
    const float* __restrict__ xg,
    unsigned short* __restrict__ HallT,       // (TT+1) x [k8 256][row 256][8]
    float* __restrict__ outh, float* __restrict__ outc) {
  extern __shared__ __align__(16) char smem[];
  short8* Wl = reinterpret_cast<short8*>(smem);   // 8192 chunks = 128 KB
  const int tid = threadIdx.x, lane = tid & 63, wave = tid >> 6;
  const int l15 = lane & 15, l4 = lane >> 4;
  const int blk = blockIdx.x;
  const int qb = blk * 32, rw = wave * 32;

  // --- one-time: W slab -> LDS (identity copy, coalesced, conflict-free) ---
  const short8* Wg = reinterpret_cast<const short8*>(Whh) + (size_t)blk * 8192;
#pragma unroll
  for (int j = 0; j < 16; ++j) Wl[tid + j * 512] = Wg[tid + j * 512];

  // --- one-time: xg fragments for this thread's fixed C-positions ---
  float xgf[2][2][4];
#pragma unroll
  for (int rt = 0; rt < 2; ++rt)
#pragma unroll
    for (int ct = 0; ct < 2; ++ct)
#pragma unroll
      for (int r = 0; r < 4; ++r)
        xgf[rt][ct][r] =
            xg[(size_t)(rw + rt * 16 + l4 * 4 + r) * G4 + qb + ct * 16 + l15];

  float creg[2][2][4] = {};   // cell state, register-resident across ticks
  __syncthreads();

  cg::grid_group grid = cg::this_grid();
  const int abase = l4 * 256 + rw + l15;      // A chunk: k8*256+row
  const short8* Lr = Wl + l4 * 32 + l15;      // W chunk: k8*32+col
  const int gate = l15 & 3, base = lane & ~3;

  for (int t = 0; t < TT; ++t) {
    if (t) grid.sync();   // h(t) fully written by all blocks
    const short8* A8 = reinterpret_cast<const short8*>(HallT) + (size_t)t * 65536;
    floatx4 acc[2][2];
#pragma unroll
    for (int rt = 0; rt < 2; ++rt)
#pragma unroll
      for (int ct = 0; ct < 2; ++ct)
#pragma unroll
        for (int r = 0; r < 4; ++r) acc[rt][ct][r] = xgf[rt][ct][r];

    short8 ring[8][2];
#pragma unroll
    for (int i = 0; i < 8; ++i) {
      ring[i][0] = A8[abase + i * 1024];
      ring[i][1] = A8[abase + i * 1024 + 16];
    }
#pragma unroll 8
    for (int kt = 0; kt < 64; ++kt) {
      short8 a0 = ring[kt & 7][0], a1 = ring[kt & 7][1];
      if (kt < 56) {
        ring[kt & 7][0] = A8[abase + (kt + 8) * 1024];
        ring[kt & 7][1] = A8[abase + (kt + 8) * 1024 + 16];
      }
      short8 b0 = Lr[kt * 128];
      short8 b1 = Lr[kt * 128 + 16];
      acc[0][0] = __builtin_amdgcn_mfma_f32_16x16x32_bf16(a0, b0, acc[0][0], 0, 0, 0);
      acc[0][1] = __builtin_amdgcn_mfma_f32_16x16x32_bf16(a0, b1, acc[0][1], 0, 0, 0);
      acc[1][0] = __builtin_amdgcn_mfma_f32_16x16x32_bf16(a1, b0, acc[1][0], 0, 0, 0);
      acc[1][1] = __builtin_amdgcn_mfma_f32_16x16x32_bf16(a1, b1, acc[1][1], 0, 0, 0);
    }

    // --- epilogue: gates -> cell update (c in regs) -> h^T write ---
    unsigned short* Ho = HallT + (size_t)(t + 1) * 524288;
#pragma unroll
    for (int rt = 0; rt < 2; ++rt)
#pragma unroll
      for (int ct = 0; ct < 2; ++ct)
#pragma unroll
        for (int r = 0; r < 4; ++r) {
          float g = acc[rt][ct][r];
          float act = (gate == 2) ? fast_tanh(g) : fast_sigmoid(g);
          float iv = __shfl(act, base);
          float fv = __shfl(act, base + 1);
          float gv = __shfl(act, base + 2);
          float ov = __shfl(act, base + 3);
          float cnew = fv * creg[rt][ct][r] + iv * gv;
          float hnew = ov * fast_tanh(cnew);
          creg[rt][ct][r] = cnew;
          if (gate == 0) {
            int row = rw + rt * 16 + l4 * 4 + r;
            int uj = ct * 4 + (l15 >> 2);
            Ho[(size_t)(blk * 256 + row) * 8 + uj] = f2bf(hnew);
            if (t == TT - 1) {
              size_t ci = (size_t)row * HH + blk * 8 + uj;
              outh[ci] = hnew;
              outc[ci] = cnew;
            }
          }
        }
  }
}

// xg = x @ W_ih^T (q-permuted cols) + b_ih + b_hh
__global__ __launch_bounds__(512) void xg_kernel(
    const unsigned short* __restrict__ XT, const unsigned short* __restrict__ Wih,
    const float* __restrict__ b_ih, const float* __restrict__ b_hh,
    float* __restrict__ xg) {
  __shared__ __align__(16) unsigned short Wlds[32768];
  floatx4 acc[2][2];
  floatx4 z4 = {0.f, 0.f, 0.f, 0.f};
  acc[0][0] = z4; acc[0][1] = z4; acc[1][0] = z4; acc[1][1] = z4;
  core_gemm(reinterpret_cast<const short8*>(XT),
            reinterpret_cast<const short8*>(Wih) + (size_t)blockIdx.x * 8192,
            reinterpret_cast<short8*>(Wlds), acc);

  const int lane = threadIdx.x & 63, wave = threadIdx.x >> 6;
  const int l15 = lane & 15, l4 = lane >> 4;
  const int qb = blockIdx.x * 32, rw = wave * 32;
#pragma unroll
  for (int rt = 0; rt < 2; ++rt)
#pragma unroll
    for (int ct = 0; ct < 2; ++ct) {
      const int q = qb + ct * 16 + l15;
      const float bias = b_ih[(q & 3) * HH + (q >> 2)] + b_hh[(q & 3) * HH + (q >> 2)];
#pragma unroll
      for (int r = 0; r < 4; ++r) {
        const int row = rw + rt * 16 + l4 * 4 + r;
        xg[(size_t)row * G4 + q] = acc[rt][ct][r] + bias;
      }
    }
}

// fe = h_t @ W_fe^T + b_fe for all t: block = (t, colgroup of 32)
__global__ __launch_bounds__(512) void fe_kernel(
    const unsigned short* __restrict__ HallT, const unsigned short* __restrict__ Wfe,
    const float* __restrict__ b_fe, float* __restrict__ fe) {
  const int t = blockIdx.x >> 2, cg_ = blockIdx.x & 3;
  __shared__ __align__(16) unsigned short Wlds[32768];
  floatx4 acc[2][2];
  floatx4 z4 = {0.f, 0.f, 0.f, 0.f};
  acc[0][0] = z4; acc[0][1] = z4; acc[1][0] = z4; acc[1][1] = z4;
  core_gemm(reinterpret_cast<const short8*>(HallT) + (size_t)(t + 1) * 65536,
            reinterpret_cast<const short8*>(Wfe) + (size_t)cg_ * 8192,
            reinterpret_cast<short8*>(Wlds), acc);

  const int tid = threadIdx.x, lane = tid & 63, wave = tid >> 6;
  const int l15 = lane & 15, l4 = lane >> 4;
  const int rw = wave * 32;
#pragma unroll
  for (int rt = 0; rt < 2; ++rt)
#pragma unroll
    for (int ct = 0; ct < 2; ++ct) {
      const int col = cg_ * 32 + ct * 16 + l15;
      const float bias = b_fe[col];
#pragma unroll
      for (int r = 0; r < 4; ++r) {
        const int row = rw + rt * 16 + l4 * 4 + r;
        fe[((size_t)t * 256 + row) * 128 + col] = acc[rt][ct][r] + bias;
      }
    }
}

// z = eps*softplus(fe[:,64:]-5) + fe[:,:64]; outputs laid out (B,K,T)
__global__ void z_kernel(const float* __restrict__ eps, const float* __restrict__ fe,
                         float* __restrict__ out) {
  const int tid = blockIdx.x * blockDim.x + threadIdx.x;  // 524288 = T*B*K
  const int tt = tid >> 14;
  const int b = (tid >> 6) & 255;
  const int k = tid & 63;
  const int frow = tt * 256 + b;
  const float mus = fe[frow * 128 + k];
  const float sig = softplusf_(fe[frow * 128 + 64 + k] - 5.0f);
  const float z = eps[tid] * sig + mus;
  const int o = (b * KK + k) * TT + tt;
  out[o] = z;
  out[524288 + o] = mus;
  out[2 * 524288 + o] = sig;
}

extern "C" void kernel_launch(void* const* d_in, const int* in_sizes, int n_in,
                              void* d_out, int out_size, void* d_ws, size_t ws_size,
                              hipStream_t stream) {
  const float* x    = (const float*)d_in[0];
  const float* eps  = (const float*)d_in[1];
  const float* W_ih = (const float*)d_in[2];
  const float* W_hh = (const float*)d_in[3];
  const float* b_ih = (const float*)d_in[4];
  const float* b_hh = (const float*)d_in[5];
  const float* W_fe = (const float*)d_in[6];
  const float* b_fe = (const float*)d_in[7];
  float* out = (float*)d_out;

  const size_t BH  = (size_t)BB * HH;       // 524288
  const size_t BKT = (size_t)BB * KK * TT;  // 524288

  char* p = (char*)d_ws;
  auto nxt = [&](size_t bytes) -> char* {
    char* r = p; p += (bytes + 255) & ~(size_t)255; return r;
  };
  unsigned short* Wbig  = (unsigned short*)nxt((size_t)G4 * HH * 2);       // W_ih then W_hh
  float*          xg    = (float*)nxt((size_t)BB * G4 * 4);
  unsigned short* HallT = (unsigned short*)nxt((size_t)(TT + 1) * BH * 2);
  unsigned short* XT    = (unsigned short*)nxt(BH * 2);
  unsigned short* Wfeb  = (unsigned short*)nxt((size_t)128 * HH * 2);
  float*          fe    = (float*)nxt((size_t)(TT * BB) * 128 * 4);

  hipMemsetAsync(HallT, 0, BH * 2, stream);  // slot 0 = h0 = 0

  cvt_x_kernel<<<256, 256, 0, stream>>>(x, XT);
  cvt_w_kernel<0><<<64, 256, 0, stream>>>(W_fe, Wfeb, 16384);
  cvt_w_kernel<1><<<4096, 256, 0, stream>>>(W_ih, Wbig, 1048576);
  xg_kernel<<<256, 512, 0, stream>>>(XT, Wbig, b_ih, b_hh, xg);
  cvt_w_kernel<1><<<4096, 256, 0, stream>>>(W_hh, Wbig, 1048576);

  float* outh = out + 3 * BKT;
  float* outc = out + 3 * BKT + BH;
  hipFuncSetAttribute((const void*)lstm_kernel,
                      hipFuncAttributeMaxDynamicSharedMemorySize, 131072);
  const unsigned short* WbigC = Wbig;
  const float* xgC = xg;
  void* args[] = { (void*)&WbigC, (void*)&xgC, (void*)&HallT,
                   (void*)&outh, (void*)&outc };
  hipLaunchCooperativeKernel((void*)lstm_kernel, dim3(256), dim3(512),
                             args, 131072, stream);

  fe_kernel<<<128, 512, 0, stream>>>(HallT, Wfeb, b_fe, fe);
  z_kernel<<<2048, 256, 0, stream>>>(eps, fe, out);
}

// Round 5
// 1584.329 us; speedup vs baseline: 1.0080x; 1.0080x over previous
//
#include <hip/hip_runtime.h>
#include <hip/hip_cooperative_groups.h>
#include <math.h>

namespace cg = cooperative_groups;

// ---------------------------------------------------------------------------
// RecurrentEncoder: LSTM (B=256, D=2048, H=2048, T=32) + emission head (K=64)
// Round 5: round-4 persistent cooperative kernel + per-block K-phase skew.
// All 256 blocks broadcast-read the same 1 MB h^T each tick; without skew
// they sweep it in lockstep -> L2 channel camping (~5.8 TB/s effective).
// Rotating each block's K start-point spreads requests across all channels.
// ---------------------------------------------------------------------------

typedef short  short8  __attribute__((ext_vector_type(8)));   // 8 x bf16
typedef float  floatx4 __attribute__((ext_vector_type(4)));

#define BB 256
#define HH 2048
#define G4 8192
#define KK 64
#define TT 32

__device__ __forceinline__ unsigned short f2bf(float f) {
  union { float f; unsigned int u; } v; v.f = f;
  unsigned int u = v.u;
  u += 0x7fffu + ((u >> 16) & 1u);   // round-to-nearest-even
  return (unsigned short)(u >> 16);
}
__device__ __forceinline__ float fast_sigmoid(float x) {
  return __builtin_amdgcn_rcpf(1.0f + __expf(-x));
}
__device__ __forceinline__ float fast_tanh(float x) {
  return 2.0f * __builtin_amdgcn_rcpf(1.0f + __expf(-2.0f * x)) - 1.0f;
}
__device__ __forceinline__ float softplusf_(float x) {
  return (x > 20.0f) ? x : log1pf(__expf(x));
}
__device__ __forceinline__ short8 cvt8(const float* __restrict__ s) {
  float4 a = reinterpret_cast<const float4*>(s)[0];
  float4 b = reinterpret_cast<const float4*>(s)[1];
  short8 o;
  o[0] = f2bf(a.x); o[1] = f2bf(a.y); o[2] = f2bf(a.z); o[3] = f2bf(a.w);
  o[4] = f2bf(b.x); o[5] = f2bf(b.y); o[6] = f2bf(b.z); o[7] = f2bf(b.w);
  return o;
}

// Weight transform: fp32 [gate-major or natural][K] -> bf16 chunks
// [blk][k8 128*2][col 32][8elem].  PERM=1: col q = u*4+g <- src row g*2048+u.
template <int PERM>
__global__ void cvt_w_kernel(const float* __restrict__ in,
                             unsigned short* __restrict__ out, int total) {
  int tid = blockIdx.x * 256 + threadIdx.x;
  if (tid >= total) return;
  int col = tid & 31;
  int k4  = (tid >> 5) & 63;    // pair index: k8 = 2*k4
  int ph  = (tid >> 11) & 1;
  int blk = tid >> 12;
  int q = blk * 32 + col;
  int srcrow = PERM ? ((q & 3) * HH + (q >> 2)) : q;
  const float* src = in + (size_t)srcrow * HH + (ph * 128 + k4 * 2) * 8;
  short8 o0 = cvt8(src);
  short8 o1 = cvt8(src + 8);
  size_t ch = ((size_t)(blk * 2 + ph) * 128 + k4 * 2) * 32 + col;
  reinterpret_cast<short8*>(out)[ch]      = o0;
  reinterpret_cast<short8*>(out)[ch + 32] = o1;
}

// x fp32 [256][2048] -> x^T chunks [k8 256][row 256][8]
__global__ void cvt_x_kernel(const float* __restrict__ in,
                             unsigned short* __restrict__ out) {
  int tid = blockIdx.x * 256 + threadIdx.x;   // 65536
  int row = tid & 255, k8 = tid >> 8;
  short8 o = cvt8(in + (size_t)row * HH + k8 * 8);
  reinterpret_cast<short8*>(out)[tid] = o;    // chunk = k8*256 + row
}

// ---------------------------------------------------------------------------
// Shared GEMM core for xg/fe kernels (2-phase LDS W staging) with K-skew.
// phase in [0,32): rotation of the 32 kt-steps within each staging phase.
// ---------------------------------------------------------------------------
__device__ __forceinline__ void core_gemm(const short8* __restrict__ A8,
                                          const short8* __restrict__ Wg8,
                                          short8* L8, floatx4 acc[2][2],
                                          int phase) {
  const int tid = threadIdx.x;
  const int lane = tid & 63, wave = tid >> 6;
  const int l15 = lane & 15, l4 = lane >> 4;
  const short8* Lr = L8 + l4 * 32 + l15;
  const int abase = l4 * 256 + wave * 32 + l15;
  for (int ph = 0; ph < 2; ++ph) {
    __syncthreads();
#pragma unroll
    for (int j = 0; j < 8; ++j)
      L8[tid + j * 512] = Wg8[ph * 4096 + tid + j * 512];
    __syncthreads();
    short8 Ar[4][2];
#pragma unroll
    for (int i = 0; i < 4; ++i) {
      int kk = (phase + i) & 31;
      Ar[i][0] = A8[abase +      (ph * 128 + kk * 4) * 256];
      Ar[i][1] = A8[abase + 16 + (ph * 128 + kk * 4) * 256];
    }
#pragma unroll 8
    for (int kt = 0; kt < 32; ++kt) {
      int kk = (phase + kt) & 31;
      short8 a0 = Ar[kt & 3][0], a1 = Ar[kt & 3][1];
      if (kt < 28) {
        int kp = (phase + kt + 4) & 31;
        Ar[kt & 3][0] = A8[abase +      (ph * 128 + kp * 4) * 256];
        Ar[kt & 3][1] = A8[abase + 16 + (ph * 128 + kp * 4) * 256];
      }
      short8 b0 = Lr[kk * 128];
      short8 b1 = Lr[kk * 128 + 16];
      acc[0][0] = __builtin_amdgcn_mfma_f32_16x16x32_bf16(a0, b0, acc[0][0], 0, 0, 0);
      acc[0][1] = __builtin_amdgcn_mfma_f32_16x16x32_bf16(a0, b1, acc[0][1], 0, 0, 0);
      acc[1][0] = __builtin_amdgcn_mfma_f32_16x16x32_bf16(a1, b0, acc[1][0], 0, 0, 0);
      acc[1][1] = __builtin_amdgcn_mfma_f32_16x16x32_bf16(a1, b1, acc[1][1], 0, 0, 0);
    }
  }
}

// ---------------------------------------------------------------------------
// Persistent LSTM: all 32 ticks in one cooperative kernel.
// Block blk owns q-cols [32blk, 32blk+32) = units [8blk, 8blk+8) x 4 gates.
// ---------------------------------------------------------------------------
__global__ __launch_bounds__(512) void lstm_kernel(
    const unsigned short* __restrict__ Whh,   // [blk][k8 256][col 32] chunks
    const float* __restrict__ xg,
    unsigned short* __restrict__ HallT,       // (TT+1) x [k8 256][row 256][8]
    float* __restrict__ outh, float* __restrict__ outc) {
  extern __shared__ __align__(16) char smem[];
  short8* Wl = reinterpret_cast<short8*>(smem);   // 8192 chunks = 128 KB
  const int tid = threadIdx.x, lane = tid & 63, wave = tid >> 6;
  const int l15 = lane & 15, l4 = lane >> 4;
  const int blk = blockIdx.x;
  const int qb = blk * 32, rw = wave * 32;
  // K-phase skew: distinct per block within an XCD (round-robin blk%8=XCD)
  const int phase = (((blk >> 3) * 2) + ((blk & 7) * 16)) & 63;

  // --- one-time: W slab -> LDS (identity copy, coalesced, conflict-free) ---
  const short8* Wg = reinterpret_cast<const short8*>(Whh) + (size_t)blk * 8192;
#pragma unroll
  for (int j = 0; j < 16; ++j) Wl[tid + j * 512] = Wg[tid + j * 512];

  // --- one-time: xg fragments for this thread's fixed C-positions ---
  float xgf[2][2][4];
#pragma unroll
  for (int rt = 0; rt < 2; ++rt)
#pragma unroll
    for (int ct = 0; ct < 2; ++ct)
#pragma unroll
      for (int r = 0; r < 4; ++r)
        xgf[rt][ct][r] =
            xg[(size_t)(rw + rt * 16 + l4 * 4 + r) * G4 + qb + ct * 16 + l15];

  float creg[2][2][4] = {};   // cell state, register-resident across ticks
  __syncthreads();

  cg::grid_group grid = cg::this_grid();
  const int abase = l4 * 256 + rw + l15;      // A chunk: k8*256+row
  const short8* Lr = Wl + l4 * 32 + l15;      // W chunk: k8*32+col
  const int gate = l15 & 3, base = lane & ~3;

  for (int t = 0; t < TT; ++t) {
    if (t) grid.sync();   // h(t) fully written by all blocks
    const short8* A8 = reinterpret_cast<const short8*>(HallT) + (size_t)t * 65536;
    floatx4 acc[2][2];
#pragma unroll
    for (int rt = 0; rt < 2; ++rt)
#pragma unroll
      for (int ct = 0; ct < 2; ++ct)
#pragma unroll
        for (int r = 0; r < 4; ++r) acc[rt][ct][r] = xgf[rt][ct][r];

    short8 ring[8][2];
#pragma unroll
    for (int i = 0; i < 8; ++i) {
      int kk = (phase + i) & 63;
      ring[i][0] = A8[abase + kk * 1024];
      ring[i][1] = A8[abase + kk * 1024 + 16];
    }
#pragma unroll 8
    for (int kt = 0; kt < 64; ++kt) {
      int kk = (phase + kt) & 63;
      short8 a0 = ring[kt & 7][0], a1 = ring[kt & 7][1];
      if (kt < 56) {
        int kp = (phase + kt + 8) & 63;
        ring[kt & 7][0] = A8[abase + kp * 1024];
        ring[kt & 7][1] = A8[abase + kp * 1024 + 16];
      }
      short8 b0 = Lr[kk * 128];
      short8 b1 = Lr[kk * 128 + 16];
      acc[0][0] = __builtin_amdgcn_mfma_f32_16x16x32_bf16(a0, b0, acc[0][0], 0, 0, 0);
      acc[0][1] = __builtin_amdgcn_mfma_f32_16x16x32_bf16(a0, b1, acc[0][1], 0, 0, 0);
      acc[1][0] = __builtin_amdgcn_mfma_f32_16x16x32_bf16(a1, b0, acc[1][0], 0, 0, 0);
      acc[1][1] = __builtin_amdgcn_mfma_f32_16x16x32_bf16(a1, b1, acc[1][1], 0, 0, 0);
    }

    // --- epilogue: gates -> cell update (c in regs) -> h^T write ---
    unsigned short* Ho = HallT + (size_t)(t + 1) * 524288;
#pragma unroll
    for (int rt = 0; rt < 2; ++rt)
#pragma unroll
      for (int ct = 0; ct < 2; ++ct)
#pragma unroll
        for (int r = 0; r < 4; ++r) {
          float g = acc[rt][ct][r];
          float act = (gate == 2) ? fast_tanh(g) : fast_sigmoid(g);
          float iv = __shfl(act, base);
          float fv = __shfl(act, base + 1);
          float gv = __shfl(act, base + 2);
          float ov = __shfl(act, base + 3);
          float cnew = fv * creg[rt][ct][r] + iv * gv;
          float hnew = ov * fast_tanh(cnew);
          creg[rt][ct][r] = cnew;
          if (gate == 0) {
            int row = rw + rt * 16 + l4 * 4 + r;
            int uj = ct * 4 + (l15 >> 2);
            Ho[(size_t)(blk * 256 + row) * 8 + uj] = f2bf(hnew);
            if (t == TT - 1) {
              size_t ci = (size_t)row * HH + blk * 8 + uj;
              outh[ci] = hnew;
              outc[ci] = cnew;
            }
          }
        }
  }
}

// xg = x @ W_ih^T (q-permuted cols) + b_ih + b_hh
__global__ __launch_bounds__(512) void xg_kernel(
    const unsigned short* __restrict__ XT, const unsigned short* __restrict__ Wih,
    const float* __restrict__ b_ih, const float* __restrict__ b_hh,
    float* __restrict__ xg) {
  __shared__ __align__(16) unsigned short Wlds[32768];
  floatx4 acc[2][2];
  floatx4 z4 = {0.f, 0.f, 0.f, 0.f};
  acc[0][0] = z4; acc[0][1] = z4; acc[1][0] = z4; acc[1][1] = z4;
  const int blk = blockIdx.x;
  const int phase = ((blk >> 3) + ((blk & 7) * 8)) & 31;
  core_gemm(reinterpret_cast<const short8*>(XT),
            reinterpret_cast<const short8*>(Wih) + (size_t)blk * 8192,
            reinterpret_cast<short8*>(Wlds), acc, phase);

  const int lane = threadIdx.x & 63, wave = threadIdx.x >> 6;
  const int l15 = lane & 15, l4 = lane >> 4;
  const int qb = blk * 32, rw = wave * 32;
#pragma unroll
  for (int rt = 0; rt < 2; ++rt)
#pragma unroll
    for (int ct = 0; ct < 2; ++ct) {
      const int q = qb + ct * 16 + l15;
      const float bias = b_ih[(q & 3) * HH + (q >> 2)] + b_hh[(q & 3) * HH + (q >> 2)];
#pragma unroll
      for (int r = 0; r < 4; ++r) {
        const int row = rw + rt * 16 + l4 * 4 + r;
        xg[(size_t)row * G4 + q] = acc[rt][ct][r] + bias;
      }
    }
}

// fe = h_t @ W_fe^T + b_fe for all t: block = (t, colgroup of 32)
__global__ __launch_bounds__(512) void fe_kernel(
    const unsigned short* __restrict__ HallT, const unsigned short* __restrict__ Wfe,
    const float* __restrict__ b_fe, float* __restrict__ fe) {
  const int t = blockIdx.x >> 2, cg_ = blockIdx.x & 3;
  __shared__ __align__(16) unsigned short Wlds[32768];
  floatx4 acc[2][2];
  floatx4 z4 = {0.f, 0.f, 0.f, 0.f};
  acc[0][0] = z4; acc[0][1] = z4; acc[1][0] = z4; acc[1][1] = z4;
  core_gemm(reinterpret_cast<const short8*>(HallT) + (size_t)(t + 1) * 65536,
            reinterpret_cast<const short8*>(Wfe) + (size_t)cg_ * 8192,
            reinterpret_cast<short8*>(Wlds), acc, (blockIdx.x * 5) & 31);

  const int tid = threadIdx.x, lane = tid & 63, wave = tid >> 6;
  const int l15 = lane & 15, l4 = lane >> 4;
  const int rw = wave * 32;
#pragma unroll
  for (int rt = 0; rt < 2; ++rt)
#pragma unroll
    for (int ct = 0; ct < 2; ++ct) {
      const int col = cg_ * 32 + ct * 16 + l15;
      const float bias = b_fe[col];
#pragma unroll
      for (int r = 0; r < 4; ++r) {
        const int row = rw + rt * 16 + l4 * 4 + r;
        fe[((size_t)t * 256 + row) * 128 + col] = acc[rt][ct][r] + bias;
      }
    }
}

// z = eps*softplus(fe[:,64:]-5) + fe[:,:64]; outputs laid out (B,K,T)
__global__ void z_kernel(const float* __restrict__ eps, const float* __restrict__ fe,
                         float* __restrict__ out) {
  const int tid = blockIdx.x * blockDim.x + threadIdx.x;  // 524288 = T*B*K
  const int tt = tid >> 14;
  const int b = (tid >> 6) & 255;
  const int k = tid & 63;
  const int frow = tt * 256 + b;
  const float mus = fe[frow * 128 + k];
  const float sig = softplusf_(fe[frow * 128 + 64 + k] - 5.0f);
  const float z = eps[tid] * sig + mus;
  const int o = (b * KK + k) * TT + tt;
  out[o] = z;
  out[524288 + o] = mus;
  out[2 * 524288 + o] = sig;
}

extern "C" void kernel_launch(void* const* d_in, const int* in_sizes, int n_in,
                              void* d_out, int out_size, void* d_ws, size_t ws_size,
                              hipStream_t stream) {
  const float* x    = (const float*)d_in[0];
  const float* eps  = (const float*)d_in[1];
  const float* W_ih = (const float*)d_in[2];
  const float* W_hh = (const float*)d_in[3];
  const float* b_ih = (const float*)d_in[4];
  const float* b_hh = (const float*)d_in[5];
  const float* W_fe = (const float*)d_in[6];
  const float* b_fe = (const float*)d_in[7];
  float* out = (float*)d_out;

  const size_t BH  = (size_t)BB * HH;       // 524288
  const size_t BKT = (size_t)BB * KK * TT;  // 524288

  char* p = (char*)d_ws;
  auto nxt = [&](size_t bytes) -> char* {
    char* r = p; p += (bytes + 255) & ~(size_t)255; return r;
  };
  unsigned short* Wbig  = (unsigned short*)nxt((size_t)G4 * HH * 2);       // W_ih then W_hh
  float*          xg    = (float*)nxt((size_t)BB * G4 * 4);
  unsigned short* HallT = (unsigned short*)nxt((size_t)(TT + 1) * BH * 2);
  unsigned short* XT    = (unsigned short*)nxt(BH * 2);
  unsigned short* Wfeb  = (unsigned short*)nxt((size_t)128 * HH * 2);
  float*          fe    = (float*)nxt((size_t)(TT * BB) * 128 * 4);

  hipMemsetAsync(HallT, 0, BH * 2, stream);  // slot 0 = h0 = 0

  cvt_x_kernel<<<256, 256, 0, stream>>>(x, XT);
  cvt_w_kernel<0><<<64, 256, 0, stream>>>(W_fe, Wfeb, 16384);
  cvt_w_kernel<1><<<4096, 256, 0, stream>>>(W_ih, Wbig, 1048576);
  xg_kernel<<<256, 512, 0, stream>>>(XT, Wbig, b_ih, b_hh, xg);
  cvt_w_kernel<1><<<4096, 256, 0, stream>>>(W_hh, Wbig, 1048576);

  float* outh = out + 3 * BKT;
  float* outc = out + 3 * BKT + BH;
  hipFuncSetAttribute((const void*)lstm_kernel,
                      hipFuncAttributeMaxDynamicSharedMemorySize, 131072);
  const unsigned short* WbigC = Wbig;
  const float* xgC = xg;
  void* args[] = { (void*)&WbigC, (void*)&xgC, (void*)&HallT,
                   (void*)&outh, (void*)&outc };
  hipLaunchCooperativeKernel((void*)lstm_kernel, dim3(256), dim3(512),
                             args, 131072, stream);

  fe_kernel<<<128, 512, 0, stream>>>(HallT, Wfeb, b_fe, fe);
  z_kernel<<<2048, 256, 0, stream>>>(eps, fe, out);
}